// Round 6
// baseline (65.681 us; speedup 1.0000x reference)
//
#include <hip/hip_runtime.h>
#include <math.h>

// LearnableHighpass biquad, B=64, T=524288, fp32.
// Chunked-parallel IIR: pole radius ~0.888 -> 128-sample zero-state warm-up
// converges state to ~3e-7 (threshold 1.075e-1).
// R6 = R5 + 2-deep software pipeline (3 live 128B stages -> 16KB/wave in
// flight, ~16MB chip-wide, above the ~5.7MB BDP; R5's 1-deep dipped below
// BDP during compute+store phases -> only 4.4 TB/s effective).
// Last TWO iterations peeled so prefetch never passes the chunk end.
// NO nontemporal stores (R4: nt bypassed L2 write-combining, 3.2x slower).

typedef float f4 __attribute__((ext_vector_type(4)));

namespace {
constexpr int T_LEN = 524288;
constexpr int B_ROWS = 64;
constexpr int LT = 512;              // per-thread chunk (samples)
constexpr int WU = 128;              // warm-up samples
constexpr int CPR = T_LEN / LT;      // 1024 chunks per row
constexpr int NV = T_LEN / 4;        // f4 vectors per row
constexpr int GV = 8;                // vectors per stage (32 samples = 128 B)
constexpr int ITERS = (WU + LT) / (4 * GV);  // 20 stages
constexpr int SKIP = WU / (4 * GV);          // 4 warm-up stages (no store)
}

__global__ __launch_bounds__(256) void hp_biquad(
    const float* __restrict__ x,
    const float* __restrict__ ffreq,
    const float* __restrict__ fqv,
    const int*  __restrict__ srv,
    float* __restrict__ y)
{
    const float fsr   = (float)srv[0];
    const float w0    = 6.28318530717958647692f * ffreq[0] / fsr;
    const float sw    = sinf(w0);
    const float cw    = cosf(w0);
    const float alpha = sw / (2.0f * fqv[0]);
    const float ia0   = 1.0f / (1.0f + alpha);
    const float b0 = 0.5f * (1.0f + cw) * ia0;
    const float b1 = -(1.0f + cw) * ia0;
    const float b2 = b0;
    const float a1 = -2.0f * cw * ia0;
    const float a2 = (1.0f - alpha) * ia0;

    const int g   = blockIdx.x * blockDim.x + threadIdx.x;
    const int row = g / CPR;
    const int ci  = g % CPR;
    if (row >= B_ROWS) return;

    const f4* __restrict__ xv = (const f4*)(x + (size_t)row * T_LEN);
    f4* __restrict__ yv       = (f4*)(y + (size_t)row * T_LEN);

    const int iStart = ci * (LT / 4);
    const int i0     = iStart - WU / 4;    // negative only for ci==0

    float xm1 = 0.f, xm2 = 0.f, ym1 = 0.f, ym2 = 0.f;

    // Max index prefetched: i0 + GV*ITERS - 1 = iStart + 127 <= NV-1 always
    // (loop prefetches only to stage ITERS-1; last two iters peeled).
    // Only the low side (ci==0 warm-up) needs handling.
    auto LD = [&](int i) -> f4 {
        int j = i < 0 ? 0 : i;
        f4 v = xv[j];
        if (i < 0) v = (f4)(0.f);
        return v;
    };

    auto step = [&](float xt) -> float {
        // off-critical-path terms first; critical path = single FMA on ym1
        float t  = b0 * xt + b1 * xm1 + b2 * xm2 - a2 * ym2;
        float yt = t - a1 * ym1;
        xm2 = xm1; xm1 = xt;
        ym2 = ym1; ym1 = yt;
        return yt;
    };
    auto proc4 = [&](f4 c) -> f4 {
        f4 o;
        o.x = step(c.x); o.y = step(c.y); o.z = step(c.z); o.w = step(c.w);
        return o;
    };
    auto store_stage = [&](const f4* o, int k) {
        const int ob = i0 + GV * k;
#pragma unroll
        for (int v = 0; v < GV; ++v) yv[ob + v] = o[v];
    };
    auto compute_stage = [&](const f4* in, int k) {
        f4 o[GV];
#pragma unroll
        for (int v = 0; v < GV; ++v) o[v] = proc4(in[v]);
        if (k >= SKIP) store_stage(o, k);   // wave-uniform branch
    };

    // 2-deep software pipeline over 8-vector (128 B) stages
    f4 buf0[GV], buf1[GV], buf2[GV];
#pragma unroll
    for (int v = 0; v < GV; ++v) buf0[v] = LD(i0 + v);
#pragma unroll
    for (int v = 0; v < GV; ++v) buf1[v] = LD(i0 + GV + v);

    for (int k = 0; k < ITERS - 2; ++k) {
        const int nb = i0 + GV * (k + 2);
#pragma unroll
        for (int v = 0; v < GV; ++v) buf2[v] = LD(nb + v);

        compute_stage(buf0, k);

#pragma unroll
        for (int v = 0; v < GV; ++v) { buf0[v] = buf1[v]; buf1[v] = buf2[v]; }
    }
    compute_stage(buf0, ITERS - 2);   // peeled: no prefetch
    compute_stage(buf1, ITERS - 1);
}

extern "C" void kernel_launch(void* const* d_in, const int* in_sizes, int n_in,
                              void* d_out, int out_size, void* d_ws, size_t ws_size,
                              hipStream_t stream) {
    const float* x  = (const float*)d_in[0];
    const float* ff = (const float*)d_in[1];
    const float* fq = (const float*)d_in[2];
    const int*   sr = (const int*)d_in[3];
    float* out = (float*)d_out;

    const int total_threads = B_ROWS * CPR;   // 65536
    const int block = 256;
    const int grid  = total_threads / block;  // 256
    hp_biquad<<<grid, block, 0, stream>>>(x, ff, fq, sr, out);
}

// Round 7
// 51.451 us; speedup vs baseline: 1.2766x; 1.2766x over previous
//
#include <hip/hip_runtime.h>
#include <math.h>

// LearnableHighpass biquad, B=64, T=524288, fp32.
// Chunked-parallel IIR (128-sample zero-state warm-up, pole^128 ~ 3e-7).
// R7: LDS wave-local transpose for COALESCED global access.
//   Old: each load/store instr = 64 lanes x 16B at 2KB stride = 64 requests.
//   New: global<->LDS cooperative, 8 lanes contiguous per 128B segment
//        = 8 requests/instr; lane's private 128B stage lives in LDS.
//   IN : global_load_lds (pre-swizzled per-lane global src, linear LDS dst),
//        counted vmcnt so next-stage loads + stores stay in flight.
//   OUT: swizzled ds_write_b128 -> linear coop ds_read_b128 -> coalesced store.
// Block = 1 wave (64 threads): no barriers needed, waitcnt only.

typedef float f4 __attribute__((ext_vector_type(4)));

namespace {
constexpr int T_LEN = 524288;
constexpr int B_ROWS = 64;
constexpr int LT = 512;                 // samples per chunk (per lane)
constexpr int WU = 128;                 // warm-up samples
constexpr int CPR = T_LEN / LT;         // 1024 chunks per row
constexpr int NV = T_LEN / 4;           // 131072 f4 vectors per row
constexpr int GV = 8;                   // f4 vectors per stage (128 B / lane)
constexpr int ITERS = (WU + LT) / (4 * GV);  // 20 stages
constexpr int SKIP = WU / (4 * GV);          // 4 warm-up stages (no store)
}

using gfp = const float __attribute__((address_space(1)))*;
using lfp = float __attribute__((address_space(3)))*;

__global__ __launch_bounds__(64) void hp_biquad(
    const float* __restrict__ x,
    const float* __restrict__ ffreq,
    const float* __restrict__ fqv,
    const int*  __restrict__ srv,
    float* __restrict__ y)
{
    // stage buffers: in double-buffered (2x8KB), out single (8KB) = 24 KB
    __shared__ f4 inb[2][512];
    __shared__ f4 outb[512];

    const float fsr   = (float)srv[0];
    const float w0    = 6.28318530717958647692f * ffreq[0] / fsr;
    const float sw    = sinf(w0);
    const float cw    = cosf(w0);
    const float alpha = sw / (2.0f * fqv[0]);
    const float ia0   = 1.0f / (1.0f + alpha);
    const float b0 = 0.5f * (1.0f + cw) * ia0;
    const float b1 = -(1.0f + cw) * ia0;
    const float b2 = b0;
    const float a1 = -2.0f * cw * ia0;
    const float a2 = (1.0f - alpha) * ia0;

    const int lane = threadIdx.x;               // 0..63 == chunk-lane l
    const int wv   = blockIdx.x;                // wave id, 0..1023
    const int c0   = wv * 64;                   // first chunk of this wave
    const int row  = c0 >> 10;                  // 1024 chunks per row
    const int c0r  = c0 & (CPR - 1);
    const bool firstWave  = (c0r == 0);
    const int rowBaseVec  = row * NV;
    const int waveVecBase = rowBaseVec + c0r * (LT / 4) - WU / 4;

    // per-lane swizzle: LDS slot (l, w) holds global vector (l, w ^ (l&7)).
    // cooperative call j, lane m -> chunk-lane l = 8j + (m>>3),
    // vector v* = (m&7) ^ ((m>>3)&7); 8 lanes cover one contiguous 128 B.
    const int vstar   = (lane & 7) ^ ((lane >> 3) & 7);
    const int laneOff = ((lane >> 3) << 7) + vstar;   // (m>>3)*128 + v*

    const f4* __restrict__ xv = (const f4*)x;
    f4* __restrict__ yv       = (f4*)y;

    auto issue_loads = [&](int k, int bufi) {
        const int base  = waveVecBase + 8 * k + laneOff;
        const bool clmp = firstWave && (k < SKIP);   // wave-uniform
#pragma unroll
        for (int j = 0; j < 8; ++j) {
            int idx = base + j * 1024;
            if (clmp) idx = idx < rowBaseVec ? rowBaseVec : idx;  // in-bounds; zeroed later
            __builtin_amdgcn_global_load_lds(
                (gfp)(const float*)(xv + idx),
                (lfp)(float*)(&inb[bufi][j * 64]), 16, 0, 0);
        }
    };

    float xm1 = 0.f, xm2 = 0.f, ym1 = 0.f, ym2 = 0.f;
    auto step = [&](float xt) -> float {
        float t  = b0 * xt + b1 * xm1 + b2 * xm2 - a2 * ym2;
        float yt = t - a1 * ym1;
        xm2 = xm1; xm1 = xt;
        ym2 = ym1; ym1 = yt;
        return yt;
    };

    issue_loads(0, 0);

    for (int k = 0; k < ITERS; ++k) {
        const int bufi = k & 1;
        if (k + 1 < ITERS) issue_loads(k + 1, bufi ^ 1);

        // vmcnt retires in issue order. Outstanding (oldest->newest):
        //   loads_k (8) [, stores_{k-1} (8) if k-1>=SKIP] [, loads_{k+1} (8)]
        // Drain exactly loads_k:
        if (k > SKIP && k + 1 < ITERS) {
            asm volatile("s_waitcnt vmcnt(16)" ::: "memory");
        } else {
            asm volatile("s_waitcnt vmcnt(8)" ::: "memory");
        }
        __builtin_amdgcn_sched_barrier(0);

        // private 128 B from LDS (swizzled slots)
        f4 r[8];
#pragma unroll
        for (int v = 0; v < 8; ++v)
            r[v] = inb[bufi][(lane << 3) + (v ^ (lane & 7))];

        if (firstWave && lane == 0 && k < SKIP) {
            // row-first chunk: warm-up indices are pre-row -> true zero state
#pragma unroll
            for (int v = 0; v < 8; ++v) r[v] = (f4)(0.f);
        }

        f4 o[8];
#pragma unroll
        for (int v = 0; v < 8; ++v) {
            o[v].x = step(r[v].x);
            o[v].y = step(r[v].y);
            o[v].z = step(r[v].z);
            o[v].w = step(r[v].w);
        }

        if (k >= SKIP) {
            // swizzled write, linear coop read -> coalesced global store
#pragma unroll
            for (int v = 0; v < 8; ++v)
                outb[(lane << 3) + (v ^ (lane & 7))] = o[v];
            f4 t[8];
#pragma unroll
            for (int j = 0; j < 8; ++j)
                t[j] = outb[(j << 6) + lane];
            const int obase = waveVecBase + 8 * k + laneOff;
#pragma unroll
            for (int j = 0; j < 8; ++j)
                yv[obase + j * 1024] = t[j];
        }
    }
}

extern "C" void kernel_launch(void* const* d_in, const int* in_sizes, int n_in,
                              void* d_out, int out_size, void* d_ws, size_t ws_size,
                              hipStream_t stream) {
    const float* x  = (const float*)d_in[0];
    const float* ff = (const float*)d_in[1];
    const float* fq = (const float*)d_in[2];
    const int*   sr = (const int*)d_in[3];
    float* out = (float*)d_out;

    const int grid  = (B_ROWS * CPR) / 64;   // 1024 waves, 1 wave per block
    const int block = 64;
    hp_biquad<<<grid, block, 0, stream>>>(x, ff, fq, sr, out);
}